// Round 7
// baseline (753.300 us; speedup 1.0000x reference)
//
#include <hip/hip_runtime.h>

#define N_NODES 100000
#define N_EDGES 1600000
#define C_H     128
#define C_OUT   40
#define K_FC    384
#define BN_EPS  1e-5f
#define NB      391        // buckets: row >> 8
#define CHUNK   6144       // edges per binning workgroup

typedef unsigned int uint;

// ---------------------------------------------------------------- utilities
__global__ void zero_i32(int* p, int n) {
    int i = blockIdx.x * blockDim.x + threadIdx.x;
    if (i < n) p[i] = 0;
}

// -------- CSR build, stage 1: per-chunk LDS histogram over 391 buckets
__global__ __launch_bounds__(256) void bucket_count(const int* __restrict__ erow,
                                                    int* __restrict__ bcnt) {
    __shared__ int cnt[NB];
    for (int i = threadIdx.x; i < NB; i += 256) cnt[i] = 0;
    __syncthreads();
    const int c0 = blockIdx.x * CHUNK;
    const int c1 = min(c0 + CHUNK, N_EDGES);
    for (int e = c0 + threadIdx.x; e < c1; e += 256)
        atomicAdd(&cnt[erow[e] >> 8], 1);
    __syncthreads();
    for (int i = threadIdx.x; i < NB; i += 256)
        if (cnt[i]) atomicAdd(&bcnt[i], cnt[i]);
}

// -------- stage 2: exclusive scan of bucket counts (single WG)
__global__ __launch_bounds__(256) void scan_buckets(const int* __restrict__ bcnt,
                                                    int* __restrict__ bstart,
                                                    int* __restrict__ bfill) {
    __shared__ int sa[512], sb[512];
    const int t = threadIdx.x;
    int v0 = (t < NB) ? bcnt[t] : 0;
    int v1 = (t + 256 < NB) ? bcnt[t + 256] : 0;
    sa[t] = v0; sa[t + 256] = v1;
    __syncthreads();
    int* src = sa; int* dst = sb;
    for (int off = 1; off < 512; off <<= 1) {
        dst[t]       = src[t]       + (t >= off ? src[t - off] : 0);
        dst[t + 256] = src[t + 256] + (t + 256 >= off ? src[t + 256 - off] : 0);
        __syncthreads();
        int* tmp = src; src = dst; dst = tmp;
    }
    if (t < NB)       { bstart[t] = src[t] - v0;             bfill[t] = src[t] - v0; }
    if (t + 256 < NB) { bstart[t + 256] = src[t + 256] - v1; bfill[t + 256] = src[t + 256] - v1; }
    if (t == 0) bstart[NB] = N_EDGES;
}

// -------- stage 3: scatter (row,col) pairs into per-bucket dense ranges
__global__ __launch_bounds__(256) void bucket_bin(const int* __restrict__ erow,
                                                  const int* __restrict__ ecol,
                                                  int* __restrict__ bfill,
                                                  int2* __restrict__ pairs) {
    __shared__ int cnt[NB];
    __shared__ int lpos[NB];
    for (int i = threadIdx.x; i < NB; i += 256) cnt[i] = 0;
    __syncthreads();
    const int c0 = blockIdx.x * CHUNK;
    const int c1 = min(c0 + CHUNK, N_EDGES);
    for (int e = c0 + threadIdx.x; e < c1; e += 256)
        atomicAdd(&cnt[erow[e] >> 8], 1);
    __syncthreads();
    for (int i = threadIdx.x; i < NB; i += 256)
        lpos[i] = cnt[i] ? atomicAdd(&bfill[i], cnt[i]) : 0;
    __syncthreads();
    for (int e = c0 + threadIdx.x; e < c1; e += 256) {
        int r = erow[e], c = ecol[e];
        int p = atomicAdd(&lpos[r >> 8], 1);
        pairs[p] = make_int2(r, c);
    }
}

// -------- stage 4: per-bucket local sort -> rowptr, dinv, cols (one WG/bucket)
__global__ __launch_bounds__(256) void bucket_csr(const int2* __restrict__ pairs,
                                                  const int* __restrict__ bstart,
                                                  int* __restrict__ rowptr,
                                                  float* __restrict__ dinv,
                                                  int* __restrict__ colsg) {
    __shared__ int lcnt[256], sa[256], sb[256], lpos[256];
    const int b = blockIdx.x;
    const int t = threadIdx.x;
    const int p0 = bstart[b], p1 = bstart[b + 1];
    lcnt[t] = 0;
    __syncthreads();
    for (int i = p0 + t; i < p1; i += 256)
        atomicAdd(&lcnt[pairs[i].x & 255], 1);
    __syncthreads();
    sa[t] = lcnt[t];
    __syncthreads();
    int* src = sa; int* dst = sb;
    for (int off = 1; off < 256; off <<= 1) {
        dst[t] = src[t] + (t >= off ? src[t - off] : 0);
        __syncthreads();
        int* tmp = src; src = dst; dst = tmp;
    }
    const int excl = src[t] - lcnt[t];
    const int r = b * 256 + t;
    if (r < N_NODES) {
        rowptr[r] = p0 + excl;
        dinv[r] = rsqrtf((float)lcnt[t] + 1.0f);
    }
    if (b == NB - 1 && t == 0) rowptr[N_NODES] = N_EDGES;
    lpos[t] = excl;
    __syncthreads();
    for (int i = p0 + t; i < p1; i += 256) {
        int2 pr = pairs[i];
        int s = atomicAdd(&lpos[pr.x & 255], 1);
        colsg[p0 + s] = pr.y;
    }
}

// relu(bn(agg + b)) = relu(agg*s + t)
__global__ void bn_coef(const float* b1, const float* g1, const float* be1,
                        const float* m1, const float* v1,
                        const float* b2, const float* g2, const float* be2,
                        const float* m2, const float* v2,
                        float* s1, float* t1, float* s2, float* t2) {
    int f = threadIdx.x;
    float sa = g1[f] * rsqrtf(v1[f] + BN_EPS);
    s1[f] = sa;
    t1[f] = (b1[f] - m1[f]) * sa + be1[f];
    float sb = g2[f] * rsqrtf(v2[f] + BN_EPS);
    s2[f] = sb;
    t2[f] = (b2[f] - m2[f]) * sb + be2[f];
}

#define FMA4(A, S, V) \
    A.x = fmaf(S, V.x, A.x); A.y = fmaf(S, V.y, A.y); \
    A.z = fmaf(S, V.z, A.z); A.w = fmaf(S, V.w, A.w);

__device__ inline uint pack_bf16x2(float a, float b) {
    uint ua = __builtin_bit_cast(uint, a);
    uint ub = __builtin_bit_cast(uint, b);
    ua += 0x7fffu + ((ua >> 16) & 1u);   // RNE
    ub += 0x7fffu + ((ub >> 16) & 1u);
    return (ua >> 16) | (ub & 0xffff0000u);
}

// -------------------- GEMM + dinv prescale: Hs(bf16) = diag(dinv) * (X @ W)
__global__ __launch_bounds__(256) void gemm_scaled(const float* __restrict__ X,
                                                   const float* __restrict__ W,
                                                   const float* __restrict__ dinv,
                                                   uint* __restrict__ Hs) {
    __shared__ float wl[64 * 128];   // k-half of W  (32 KB)
    __shared__ float xl[32 * 68];    // 32 rows x 64 cols, stride 68

    const int tid = threadIdx.x;
    const int rg = tid >> 5;
    const int c4 = (tid & 31) << 2;
    const int rb = blockIdx.x * 32;
    const int r0 = rb + rg * 4;

    float4 acc0 = {0,0,0,0}, acc1 = {0,0,0,0}, acc2 = {0,0,0,0}, acc3 = {0,0,0,0};

    for (int half = 0; half < 2; ++half) {
        const int k0 = half * 64;
        __syncthreads();
        {
            const float4* W4 = (const float4*)(W + (size_t)k0 * 128);
            float4* wl4 = (float4*)wl;
            #pragma unroll
            for (int i = 0; i < 8; ++i) wl4[tid + i * 256] = W4[tid + i * 256];
        }
        #pragma unroll
        for (int i = 0; i < 2; ++i) {
            int f = tid + i * 256;
            int row = f >> 4, cc = f & 15;
            float4 v = *(const float4*)(X + (size_t)(rb + row) * 128 + k0 + cc * 4);
            *(float4*)&xl[row * 68 + cc * 4] = v;
        }
        __syncthreads();

        for (int k4 = 0; k4 < 16; ++k4) {
            const float* wr = wl + k4 * 4 * 128 + c4;
            float4 w0 = *(const float4*)(wr);
            float4 w1 = *(const float4*)(wr + 128);
            float4 w2 = *(const float4*)(wr + 256);
            float4 w3 = *(const float4*)(wr + 384);
            float4 xv0 = *(const float4*)&xl[(rg * 4 + 0) * 68 + k4 * 4];
            float4 xv1 = *(const float4*)&xl[(rg * 4 + 1) * 68 + k4 * 4];
            float4 xv2 = *(const float4*)&xl[(rg * 4 + 2) * 68 + k4 * 4];
            float4 xv3 = *(const float4*)&xl[(rg * 4 + 3) * 68 + k4 * 4];
            FMA4(acc0, xv0.x, w0) FMA4(acc0, xv0.y, w1) FMA4(acc0, xv0.z, w2) FMA4(acc0, xv0.w, w3)
            FMA4(acc1, xv1.x, w0) FMA4(acc1, xv1.y, w1) FMA4(acc1, xv1.z, w2) FMA4(acc1, xv1.w, w3)
            FMA4(acc2, xv2.x, w0) FMA4(acc2, xv2.y, w1) FMA4(acc2, xv2.z, w2) FMA4(acc2, xv2.w, w3)
            FMA4(acc3, xv3.x, w0) FMA4(acc3, xv3.y, w1) FMA4(acc3, xv3.z, w2) FMA4(acc3, xv3.w, w3)
        }
    }
    float d0 = dinv[r0], d1 = dinv[r0 + 1], d2 = dinv[r0 + 2], d3 = dinv[r0 + 3];
    uint2 o;
    o.x = pack_bf16x2(acc0.x * d0, acc0.y * d0);
    o.y = pack_bf16x2(acc0.z * d0, acc0.w * d0);
    *(uint2*)(Hs + (size_t)(r0 + 0) * 64 + (c4 >> 1)) = o;
    o.x = pack_bf16x2(acc1.x * d1, acc1.y * d1);
    o.y = pack_bf16x2(acc1.z * d1, acc1.w * d1);
    *(uint2*)(Hs + (size_t)(r0 + 1) * 64 + (c4 >> 1)) = o;
    o.x = pack_bf16x2(acc2.x * d2, acc2.y * d2);
    o.y = pack_bf16x2(acc2.z * d2, acc2.w * d2);
    *(uint2*)(Hs + (size_t)(r0 + 2) * 64 + (c4 >> 1)) = o;
    o.x = pack_bf16x2(acc3.x * d3, acc3.y * d3);
    o.y = pack_bf16x2(acc3.z * d3, acc3.w * d3);
    *(uint2*)(Hs + (size_t)(r0 + 3) * 64 + (c4 >> 1)) = o;
}

// -------------------- SpMM on prescaled bf16 Hs: one wave per row, 2ch/lane.
// 16-deep gather pipeline, then 4, then 1.
#define ACC1(V) \
    accx += __builtin_bit_cast(float, V << 16); \
    accy += __builtin_bit_cast(float, V & 0xffff0000u);

__global__ __launch_bounds__(256) void spmm_bn_relu4(
    const uint* __restrict__ Hs, const int* __restrict__ cols,
    const int* __restrict__ rowptr, const float* __restrict__ dinv,
    const float* __restrict__ s, const float* __restrict__ t,
    float* __restrict__ Y) {
    const int lane = threadIdx.x & 63;
    const int r = blockIdx.x * 4 + (threadIdx.x >> 6);

    uint vself = Hs[(size_t)r * 64 + lane];
    float accx = __builtin_bit_cast(float, vself << 16);
    float accy = __builtin_bit_cast(float, vself & 0xffff0000u);
    const float di = dinv[r];
    const int e0 = rowptr[r], e1 = rowptr[r + 1];
    int j = e0;
    const int n16 = e0 + ((e1 - e0) & ~15);
    for (; j < n16; j += 16) {
        uint v[16];
        #pragma unroll
        for (int q = 0; q < 16; ++q)
            v[q] = Hs[(size_t)cols[j + q] * 64 + lane];
        #pragma unroll
        for (int q = 0; q < 16; ++q) { ACC1(v[q]) }
    }
    const int n4 = e0 + ((e1 - e0) & ~3);
    for (; j < n4; j += 4) {
        uint v[4];
        #pragma unroll
        for (int q = 0; q < 4; ++q)
            v[q] = Hs[(size_t)cols[j + q] * 64 + lane];
        #pragma unroll
        for (int q = 0; q < 4; ++q) { ACC1(v[q]) }
    }
    for (; j < e1; ++j) {
        uint v0 = Hs[(size_t)cols[j] * 64 + lane];
        ACC1(v0)
    }
    float2 sf = ((const float2*)s)[lane];
    float2 tf = ((const float2*)t)[lane];
    float2 o;
    o.x = fmaxf(fmaf(accx * di, sf.x, tf.x), 0.0f);
    o.y = fmaxf(fmaf(accy * di, sf.y, tf.y), 0.0f);
    ((float2*)Y)[(size_t)r * 64 + lane] = o;
}

// -------------------- final FC: out = [x0|x1|x2] @ fcW + fcb  (384 -> 40)
// v13: one WAVE = one BLOCK = 64 rows; each lane owns one row and ALL 40
// outputs. Synthesis of 6 rounds of counter evidence:
//  - all 40 cols from one X read (v12's 4-block split quadrupled FETCH)
//  - W wave-uniform -> s_load const cache (no per-lane W traffic at all)
//  - coalesced staging: 4 float4 instrs/chunk, each 16 rows x 64B = 16
//    lines/instr (v11's lane=row scatter was 64 lines/instr -> TA wall)
//  - wave-private dbuf LDS, ZERO barriers (v7/v10: hipcc's vmcnt(0) drain
//    at __syncthreads serialized chunks at full exposed latency)
//  - LDS stride 17 floats, scalar b32 access: read bank (17*l+k)%32 ->
//    exactly 2 lanes/bank (free); v12's b128 stride-20 was 8-way
//  - plain runtime ch-loop, named g0..g3 float4s only (v8/v9: unrolled
//    rotating slots -> VGPR 208)
// Pipeline: compute(ch) | store(ch+1) waits its loads (issued at ch-1,
// covered by ~1300cy of FMA) | issue(ch+2). Grid 1563 1-wave blocks,
// 6.1 waves/CU, perfectly balanced; FMA floor ~20us.
__global__ __launch_bounds__(64) void final_gemm13(
    const float* __restrict__ X0, const float* __restrict__ X1,
    const float* __restrict__ X2, const float* __restrict__ fcW,
    const float* __restrict__ fcb, float* __restrict__ out) {
    __shared__ float xs[2 * 64 * 17];   // 8704 B, wave-private

    const int lane = threadIdx.x;       // 64-thread block = one wave
    const int rb = blockIdx.x * 64;
    const int sr = lane >> 2;           // staging row within 16-group
    const int qk = lane & 3;            // 16B piece within row's 64B chunk

    float acc[40];
    #pragma unroll
    for (int c = 0; c < 40; ++c) acc[c] = 0.0f;

    float4 g0, g1, g2, g3;              // one named in-flight set

    // chunk ch (0..23): 16 k-floats. segment ch/8, k-offset (ch%8)*16.
    auto issue = [&](int ch) {
        const float* xseg = (ch < 8) ? X0 : (ch < 16) ? X1 : X2;
        const int koff = (ch & 7) * 16 + qk * 4;
        int r0 = rb + 0 + sr, r1 = rb + 16 + sr, r2 = rb + 32 + sr, r3 = rb + 48 + sr;
        float4 z = {0, 0, 0, 0};
        g0 = (r0 < N_NODES) ? *(const float4*)(xseg + (size_t)r0 * 128 + koff) : z;
        g1 = (r1 < N_NODES) ? *(const float4*)(xseg + (size_t)r1 * 128 + koff) : z;
        g2 = (r2 < N_NODES) ? *(const float4*)(xseg + (size_t)r2 * 128 + koff) : z;
        g3 = (r3 < N_NODES) ? *(const float4*)(xseg + (size_t)r3 * 128 + koff) : z;
    };
    // scalar b32 stores, row stride 17 -> ~2-way max on writes, 0 on reads
    auto store = [&](int buf) {
        float* b = xs + buf * 1088 + qk * 4;
        float* p0 = b + ( 0 + sr) * 17;
        p0[0] = g0.x; p0[1] = g0.y; p0[2] = g0.z; p0[3] = g0.w;
        float* p1 = b + (16 + sr) * 17;
        p1[0] = g1.x; p1[1] = g1.y; p1[2] = g1.z; p1[3] = g1.w;
        float* p2 = b + (32 + sr) * 17;
        p2[0] = g2.x; p2[1] = g2.y; p2[2] = g2.z; p2[3] = g2.w;
        float* p3 = b + (48 + sr) * 17;
        p3[0] = g3.x; p3[1] = g3.y; p3[2] = g3.z; p3[3] = g3.w;
    };

    issue(0);
    store(0);           // one exposed-latency wait, prologue only
    issue(1);

    for (int ch = 0; ch < 24; ++ch) {
        const float* rowp = xs + (ch & 1) * 1088 + lane * 17;
        const int kb = ch * 16;
        #pragma unroll
        for (int k = 0; k < 16; ++k) {
            float xv = rowp[k];                        // ds_read_b32, 2-way
            const float* wk = fcW + (size_t)(kb + k) * 40;   // uniform->s_load
            #pragma unroll
            for (int c = 0; c < 40; ++c)
                acc[c] = fmaf(xv, wk[c], acc[c]);
        }
        if (ch < 23) store((ch + 1) & 1);   // waits only its own loads
        if (ch < 22) issue(ch + 2);         // in flight across next compute
    }

    const int r = rb + lane;
    if (r < N_NODES) {
        #pragma unroll
        for (int c4 = 0; c4 < 10; ++c4) {
            float4 o;
            o.x = acc[c4 * 4 + 0] + fcb[c4 * 4 + 0];
            o.y = acc[c4 * 4 + 1] + fcb[c4 * 4 + 1];
            o.z = acc[c4 * 4 + 2] + fcb[c4 * 4 + 2];
            o.w = acc[c4 * 4 + 3] + fcb[c4 * 4 + 3];
            *(float4*)(out + (size_t)r * 40 + c4 * 4) = o;
        }
    }
}

// ---------------------------------------------------------------------------
extern "C" void kernel_launch(void* const* d_in, const int* in_sizes, int n_in,
                              void* d_out, int out_size, void* d_ws, size_t ws_size,
                              hipStream_t stream) {
    const float* x   = (const float*)d_in[0];
    const int*   ei  = (const int*)d_in[1];
    const int* e_row = ei;
    const int* e_col = ei + N_EDGES;
    const float* W1  = (const float*)d_in[2];
    const float* b1  = (const float*)d_in[3];
    const float* W2  = (const float*)d_in[4];
    const float* b2  = (const float*)d_in[5];
    const float* g1  = (const float*)d_in[6];
    const float* be1 = (const float*)d_in[7];
    const float* m1  = (const float*)d_in[8];
    const float* v1  = (const float*)d_in[9];
    const float* g2  = (const float*)d_in[10];
    const float* be2 = (const float*)d_in[11];
    const float* m2  = (const float*)d_in[12];
    const float* v2  = (const float*)d_in[13];
    const float* fcW = (const float*)d_in[14];
    const float* fcb = (const float*)d_in[15];
    float* out = (float*)d_out;

    char* ws = (char*)d_ws;
    size_t off = 0;
    auto alloc = [&](size_t b) {
        char* p = ws + off;
        off += (b + 255) & ~(size_t)255;
        return p;
    };
    uint*  h      = (uint*)alloc((size_t)N_NODES * C_H * 2);     // bf16 Hs
    float* x1     = (float*)alloc((size_t)N_NODES * C_H * 4);
    float* x2     = (float*)alloc((size_t)N_NODES * C_H * 4);
    int2*  pairs  = (int2*)alloc((size_t)N_EDGES * 8);
    int*   cols   = (int*)alloc((size_t)N_EDGES * 4);
    float* dinv   = (float*)alloc(N_NODES * 4);
    int*   rowptr = (int*)alloc((N_NODES + 1) * 4);
    int*   bcnt   = (int*)alloc((NB + 1) * 4);
    int*   bstart = (int*)alloc((NB + 1) * 4);
    int*   bfill  = (int*)alloc((NB + 1) * 4);
    float* coef   = (float*)alloc(512 * 4);
    float* s1 = coef, *t1 = coef + 128, *s2 = coef + 256, *t2 = coef + 384;

    const int nwg_bin = (N_EDGES + CHUNK - 1) / CHUNK;   // 261

    zero_i32<<<2, 256, 0, stream>>>(bcnt, NB);
    bucket_count<<<nwg_bin, 256, 0, stream>>>(e_row, bcnt);
    scan_buckets<<<1, 256, 0, stream>>>(bcnt, bstart, bfill);
    bucket_bin<<<nwg_bin, 256, 0, stream>>>(e_row, e_col, bfill, pairs);
    bucket_csr<<<NB, 256, 0, stream>>>(pairs, bstart, rowptr, dinv, cols);
    bn_coef<<<1, 128, 0, stream>>>(b1, g1, be1, m1, v1, b2, g2, be2, m2, v2,
                                   s1, t1, s2, t2);

    gemm_scaled<<<N_NODES / 32, 256, 0, stream>>>(x, W1, dinv, h);
    spmm_bn_relu4<<<N_NODES / 4, 256, 0, stream>>>(h, cols, rowptr, dinv, s1, t1, x1);
    gemm_scaled<<<N_NODES / 32, 256, 0, stream>>>(x1, W2, dinv, h);
    spmm_bn_relu4<<<N_NODES / 4, 256, 0, stream>>>(h, cols, rowptr, dinv, s2, t2, x2);
    final_gemm13<<<(N_NODES + 63) / 64, 64, 0, stream>>>(x, x1, x2, fcW, fcb, out);
}

// Round 8
// 514.323 us; speedup vs baseline: 1.4646x; 1.4646x over previous
//
#include <hip/hip_runtime.h>

#define N_NODES 100000
#define N_EDGES 1600000
#define C_H     128
#define C_OUT   40
#define K_FC    384
#define BN_EPS  1e-5f
#define NB      391        // buckets: row >> 8
#define CHUNK   6144       // edges per binning workgroup

typedef unsigned int uint;

// ---------------------------------------------------------------- utilities
__global__ void zero_i32(int* p, int n) {
    int i = blockIdx.x * blockDim.x + threadIdx.x;
    if (i < n) p[i] = 0;
}

// -------- CSR build, stage 1: per-chunk LDS histogram over 391 buckets
__global__ __launch_bounds__(256) void bucket_count(const int* __restrict__ erow,
                                                    int* __restrict__ bcnt) {
    __shared__ int cnt[NB];
    for (int i = threadIdx.x; i < NB; i += 256) cnt[i] = 0;
    __syncthreads();
    const int c0 = blockIdx.x * CHUNK;
    const int c1 = min(c0 + CHUNK, N_EDGES);
    for (int e = c0 + threadIdx.x; e < c1; e += 256)
        atomicAdd(&cnt[erow[e] >> 8], 1);
    __syncthreads();
    for (int i = threadIdx.x; i < NB; i += 256)
        if (cnt[i]) atomicAdd(&bcnt[i], cnt[i]);
}

// -------- stage 2: exclusive scan of bucket counts (single WG)
__global__ __launch_bounds__(256) void scan_buckets(const int* __restrict__ bcnt,
                                                    int* __restrict__ bstart,
                                                    int* __restrict__ bfill) {
    __shared__ int sa[512], sb[512];
    const int t = threadIdx.x;
    int v0 = (t < NB) ? bcnt[t] : 0;
    int v1 = (t + 256 < NB) ? bcnt[t + 256] : 0;
    sa[t] = v0; sa[t + 256] = v1;
    __syncthreads();
    int* src = sa; int* dst = sb;
    for (int off = 1; off < 512; off <<= 1) {
        dst[t]       = src[t]       + (t >= off ? src[t - off] : 0);
        dst[t + 256] = src[t + 256] + (t + 256 >= off ? src[t + 256 - off] : 0);
        __syncthreads();
        int* tmp = src; src = dst; dst = tmp;
    }
    if (t < NB)       { bstart[t] = src[t] - v0;             bfill[t] = src[t] - v0; }
    if (t + 256 < NB) { bstart[t + 256] = src[t + 256] - v1; bfill[t + 256] = src[t + 256] - v1; }
    if (t == 0) bstart[NB] = N_EDGES;
}

// -------- stage 3: scatter (row,col) pairs into per-bucket dense ranges
__global__ __launch_bounds__(256) void bucket_bin(const int* __restrict__ erow,
                                                  const int* __restrict__ ecol,
                                                  int* __restrict__ bfill,
                                                  int2* __restrict__ pairs) {
    __shared__ int cnt[NB];
    __shared__ int lpos[NB];
    for (int i = threadIdx.x; i < NB; i += 256) cnt[i] = 0;
    __syncthreads();
    const int c0 = blockIdx.x * CHUNK;
    const int c1 = min(c0 + CHUNK, N_EDGES);
    for (int e = c0 + threadIdx.x; e < c1; e += 256)
        atomicAdd(&cnt[erow[e] >> 8], 1);
    __syncthreads();
    for (int i = threadIdx.x; i < NB; i += 256)
        lpos[i] = cnt[i] ? atomicAdd(&bfill[i], cnt[i]) : 0;
    __syncthreads();
    for (int e = c0 + threadIdx.x; e < c1; e += 256) {
        int r = erow[e], c = ecol[e];
        int p = atomicAdd(&lpos[r >> 8], 1);
        pairs[p] = make_int2(r, c);
    }
}

// -------- stage 4: per-bucket local sort -> rowptr, dinv, cols (one WG/bucket)
__global__ __launch_bounds__(256) void bucket_csr(const int2* __restrict__ pairs,
                                                  const int* __restrict__ bstart,
                                                  int* __restrict__ rowptr,
                                                  float* __restrict__ dinv,
                                                  int* __restrict__ colsg) {
    __shared__ int lcnt[256], sa[256], sb[256], lpos[256];
    const int b = blockIdx.x;
    const int t = threadIdx.x;
    const int p0 = bstart[b], p1 = bstart[b + 1];
    lcnt[t] = 0;
    __syncthreads();
    for (int i = p0 + t; i < p1; i += 256)
        atomicAdd(&lcnt[pairs[i].x & 255], 1);
    __syncthreads();
    sa[t] = lcnt[t];
    __syncthreads();
    int* src = sa; int* dst = sb;
    for (int off = 1; off < 256; off <<= 1) {
        dst[t] = src[t] + (t >= off ? src[t - off] : 0);
        __syncthreads();
        int* tmp = src; src = dst; dst = tmp;
    }
    const int excl = src[t] - lcnt[t];
    const int r = b * 256 + t;
    if (r < N_NODES) {
        rowptr[r] = p0 + excl;
        dinv[r] = rsqrtf((float)lcnt[t] + 1.0f);
    }
    if (b == NB - 1 && t == 0) rowptr[N_NODES] = N_EDGES;
    lpos[t] = excl;
    __syncthreads();
    for (int i = p0 + t; i < p1; i += 256) {
        int2 pr = pairs[i];
        int s = atomicAdd(&lpos[pr.x & 255], 1);
        colsg[p0 + s] = pr.y;
    }
}

// relu(bn(agg + b)) = relu(agg*s + t)
__global__ void bn_coef(const float* b1, const float* g1, const float* be1,
                        const float* m1, const float* v1,
                        const float* b2, const float* g2, const float* be2,
                        const float* m2, const float* v2,
                        float* s1, float* t1, float* s2, float* t2) {
    int f = threadIdx.x;
    float sa = g1[f] * rsqrtf(v1[f] + BN_EPS);
    s1[f] = sa;
    t1[f] = (b1[f] - m1[f]) * sa + be1[f];
    float sb = g2[f] * rsqrtf(v2[f] + BN_EPS);
    s2[f] = sb;
    t2[f] = (b2[f] - m2[f]) * sb + be2[f];
}

#define FMA4(A, S, V) \
    A.x = fmaf(S, V.x, A.x); A.y = fmaf(S, V.y, A.y); \
    A.z = fmaf(S, V.z, A.z); A.w = fmaf(S, V.w, A.w);

__device__ inline uint pack_bf16x2(float a, float b) {
    uint ua = __builtin_bit_cast(uint, a);
    uint ub = __builtin_bit_cast(uint, b);
    ua += 0x7fffu + ((ua >> 16) & 1u);   // RNE
    ub += 0x7fffu + ((ub >> 16) & 1u);
    return (ua >> 16) | (ub & 0xffff0000u);
}

// -------------------- GEMM + dinv prescale: Hs(bf16) = diag(dinv) * (X @ W)
__global__ __launch_bounds__(256) void gemm_scaled(const float* __restrict__ X,
                                                   const float* __restrict__ W,
                                                   const float* __restrict__ dinv,
                                                   uint* __restrict__ Hs) {
    __shared__ float wl[64 * 128];   // k-half of W  (32 KB)
    __shared__ float xl[32 * 68];    // 32 rows x 64 cols, stride 68

    const int tid = threadIdx.x;
    const int rg = tid >> 5;
    const int c4 = (tid & 31) << 2;
    const int rb = blockIdx.x * 32;
    const int r0 = rb + rg * 4;

    float4 acc0 = {0,0,0,0}, acc1 = {0,0,0,0}, acc2 = {0,0,0,0}, acc3 = {0,0,0,0};

    for (int half = 0; half < 2; ++half) {
        const int k0 = half * 64;
        __syncthreads();
        {
            const float4* W4 = (const float4*)(W + (size_t)k0 * 128);
            float4* wl4 = (float4*)wl;
            #pragma unroll
            for (int i = 0; i < 8; ++i) wl4[tid + i * 256] = W4[tid + i * 256];
        }
        #pragma unroll
        for (int i = 0; i < 2; ++i) {
            int f = tid + i * 256;
            int row = f >> 4, cc = f & 15;
            float4 v = *(const float4*)(X + (size_t)(rb + row) * 128 + k0 + cc * 4);
            *(float4*)&xl[row * 68 + cc * 4] = v;
        }
        __syncthreads();

        for (int k4 = 0; k4 < 16; ++k4) {
            const float* wr = wl + k4 * 4 * 128 + c4;
            float4 w0 = *(const float4*)(wr);
            float4 w1 = *(const float4*)(wr + 128);
            float4 w2 = *(const float4*)(wr + 256);
            float4 w3 = *(const float4*)(wr + 384);
            float4 xv0 = *(const float4*)&xl[(rg * 4 + 0) * 68 + k4 * 4];
            float4 xv1 = *(const float4*)&xl[(rg * 4 + 1) * 68 + k4 * 4];
            float4 xv2 = *(const float4*)&xl[(rg * 4 + 2) * 68 + k4 * 4];
            float4 xv3 = *(const float4*)&xl[(rg * 4 + 3) * 68 + k4 * 4];
            FMA4(acc0, xv0.x, w0) FMA4(acc0, xv0.y, w1) FMA4(acc0, xv0.z, w2) FMA4(acc0, xv0.w, w3)
            FMA4(acc1, xv1.x, w0) FMA4(acc1, xv1.y, w1) FMA4(acc1, xv1.z, w2) FMA4(acc1, xv1.w, w3)
            FMA4(acc2, xv2.x, w0) FMA4(acc2, xv2.y, w1) FMA4(acc2, xv2.z, w2) FMA4(acc2, xv2.w, w3)
            FMA4(acc3, xv3.x, w0) FMA4(acc3, xv3.y, w1) FMA4(acc3, xv3.z, w2) FMA4(acc3, xv3.w, w3)
        }
    }
    float d0 = dinv[r0], d1 = dinv[r0 + 1], d2 = dinv[r0 + 2], d3 = dinv[r0 + 3];
    uint2 o;
    o.x = pack_bf16x2(acc0.x * d0, acc0.y * d0);
    o.y = pack_bf16x2(acc0.z * d0, acc0.w * d0);
    *(uint2*)(Hs + (size_t)(r0 + 0) * 64 + (c4 >> 1)) = o;
    o.x = pack_bf16x2(acc1.x * d1, acc1.y * d1);
    o.y = pack_bf16x2(acc1.z * d1, acc1.w * d1);
    *(uint2*)(Hs + (size_t)(r0 + 1) * 64 + (c4 >> 1)) = o;
    o.x = pack_bf16x2(acc2.x * d2, acc2.y * d2);
    o.y = pack_bf16x2(acc2.z * d2, acc2.w * d2);
    *(uint2*)(Hs + (size_t)(r0 + 2) * 64 + (c4 >> 1)) = o;
    o.x = pack_bf16x2(acc3.x * d3, acc3.y * d3);
    o.y = pack_bf16x2(acc3.z * d3, acc3.w * d3);
    *(uint2*)(Hs + (size_t)(r0 + 3) * 64 + (c4 >> 1)) = o;
}

// -------------------- SpMM on prescaled bf16 Hs: one wave per row, 2ch/lane.
// 16-deep gather pipeline, then 4, then 1.
#define ACC1(V) \
    accx += __builtin_bit_cast(float, V << 16); \
    accy += __builtin_bit_cast(float, V & 0xffff0000u);

__global__ __launch_bounds__(256) void spmm_bn_relu4(
    const uint* __restrict__ Hs, const int* __restrict__ cols,
    const int* __restrict__ rowptr, const float* __restrict__ dinv,
    const float* __restrict__ s, const float* __restrict__ t,
    float* __restrict__ Y) {
    const int lane = threadIdx.x & 63;
    const int r = blockIdx.x * 4 + (threadIdx.x >> 6);

    uint vself = Hs[(size_t)r * 64 + lane];
    float accx = __builtin_bit_cast(float, vself << 16);
    float accy = __builtin_bit_cast(float, vself & 0xffff0000u);
    const float di = dinv[r];
    const int e0 = rowptr[r], e1 = rowptr[r + 1];
    int j = e0;
    const int n16 = e0 + ((e1 - e0) & ~15);
    for (; j < n16; j += 16) {
        uint v[16];
        #pragma unroll
        for (int q = 0; q < 16; ++q)
            v[q] = Hs[(size_t)cols[j + q] * 64 + lane];
        #pragma unroll
        for (int q = 0; q < 16; ++q) { ACC1(v[q]) }
    }
    const int n4 = e0 + ((e1 - e0) & ~3);
    for (; j < n4; j += 4) {
        uint v[4];
        #pragma unroll
        for (int q = 0; q < 4; ++q)
            v[q] = Hs[(size_t)cols[j + q] * 64 + lane];
        #pragma unroll
        for (int q = 0; q < 4; ++q) { ACC1(v[q]) }
    }
    for (; j < e1; ++j) {
        uint v0 = Hs[(size_t)cols[j] * 64 + lane];
        ACC1(v0)
    }
    float2 sf = ((const float2*)s)[lane];
    float2 tf = ((const float2*)t)[lane];
    float2 o;
    o.x = fmaxf(fmaf(accx * di, sf.x, tf.x), 0.0f);
    o.y = fmaxf(fmaf(accy * di, sf.y, tf.y), 0.0f);
    ((float2*)Y)[(size_t)r * 64 + lane] = o;
}

// -------------------- final FC: out = [x0|x1|x2] @ fcW + fcb  (384 -> 40)
// v14 = v11 (best measured, 94.5us) + ONE isolated change: batched
// ping-pong loads. v11's counters showed VGPR=16 -> exactly one 16B load
// in flight per thread -> every load's full latency exposed before its 40
// FMAs (VALUBusy 22%). v13's redesign regressed 3.7x (cause unresolved;
// likely W left the scalar path), so per rigor.md: return to best, change
// one thing. Here: two named float4 quads a0..a3 / b0..b3 ping-pong over
// 64B row-chunks in a RUNTIME p-loop (no unroll pragma -- v8/v9 lesson).
// Next batch issues before each 160-FMA block -> 4-8 loads in flight,
// each batch covered by ~320 cy of FMAs. Everything else identical to
// v11: thread=row, 4 col-group waves/block sharing X lines via L1 (FETCH
// stays ~76MB), W scalarized via readfirstlane (proven s_load path).
__global__ __launch_bounds__(256) void final_gemm14(
    const float* __restrict__ X0, const float* __restrict__ X1,
    const float* __restrict__ X2, const float* __restrict__ fcW,
    const float* __restrict__ fcb, float* __restrict__ out) {
    const int t = threadIdx.x;
    const int lane = t & 63;
    const int wq = __builtin_amdgcn_readfirstlane(t >> 6);  // col group, SGPR
    const float* wbase = fcW + wq * 10;                     // uniform pointer
    const int r = blockIdx.x * 64 + lane;
    if (r >= N_NODES) return;

    float acc[10];
    #pragma unroll
    for (int c = 0; c < 10; ++c) acc[c] = 0.0f;

    float4 a0, a1, a2, a3, b0, b1, b2, b3;   // two named in-flight batches

    // chunk ch (0..23) = 16 k-floats = one 64B line of this thread's row
#define LOADB(CH, V0, V1, V2, V3) do {                                       \
    const float* xb_ = (((CH) < 8) ? X0 : ((CH) < 16) ? X1 : X2)             \
                       + (size_t)r * 128 + ((CH) & 7) * 16;                  \
    V0 = *(const float4*)(xb_ + 0);                                          \
    V1 = *(const float4*)(xb_ + 4);                                          \
    V2 = *(const float4*)(xb_ + 8);                                          \
    V3 = *(const float4*)(xb_ + 12);                                         \
} while (0)

    // 160 FMAs: 16 k-values x 10 cols, W rows via uniform s_load
#define FMAB(CH, V0, V1, V2, V3) do {                                        \
    const float* wk_ = wbase + (size_t)(CH) * 640;                           \
    _Pragma("unroll")                                                        \
    for (int q = 0; q < 4; ++q) {                                            \
        float4 v_ = (q == 0) ? V0 : (q == 1) ? V1 : (q == 2) ? V2 : V3;      \
        const float* w0_ = wk_ + q * 160;                                    \
        _Pragma("unroll")                                                    \
        for (int c = 0; c < 10; ++c) {                                       \
            acc[c] = fmaf(v_.x, w0_[c],       acc[c]);                       \
            acc[c] = fmaf(v_.y, w0_[40 + c],  acc[c]);                       \
            acc[c] = fmaf(v_.z, w0_[80 + c],  acc[c]);                       \
            acc[c] = fmaf(v_.w, w0_[120 + c], acc[c]);                       \
        }                                                                    \
    }                                                                        \
} while (0)

    LOADB(0, a0, a1, a2, a3);
    for (int p = 0; p < 12; ++p) {           // runtime loop, NO unroll
        const int ce = 2 * p, co = 2 * p + 1;
        LOADB(co, b0, b1, b2, b3);           // in flight during FMAB(ce)
        FMAB(ce, a0, a1, a2, a3);
        if (p < 11) LOADB(ce + 2, a0, a1, a2, a3);   // in flight during odd
        FMAB(co, b0, b1, b2, b3);
    }

#undef LOADB
#undef FMAB

    #pragma unroll
    for (int c2 = 0; c2 < 5; ++c2) {
        float2 o;
        o.x = acc[c2 * 2 + 0] + fcb[wq * 10 + c2 * 2 + 0];
        o.y = acc[c2 * 2 + 1] + fcb[wq * 10 + c2 * 2 + 1];
        *(float2*)(out + (size_t)r * 40 + wq * 10 + c2 * 2) = o;
    }
}

// ---------------------------------------------------------------------------
extern "C" void kernel_launch(void* const* d_in, const int* in_sizes, int n_in,
                              void* d_out, int out_size, void* d_ws, size_t ws_size,
                              hipStream_t stream) {
    const float* x   = (const float*)d_in[0];
    const int*   ei  = (const int*)d_in[1];
    const int* e_row = ei;
    const int* e_col = ei + N_EDGES;
    const float* W1  = (const float*)d_in[2];
    const float* b1  = (const float*)d_in[3];
    const float* W2  = (const float*)d_in[4];
    const float* b2  = (const float*)d_in[5];
    const float* g1  = (const float*)d_in[6];
    const float* be1 = (const float*)d_in[7];
    const float* m1  = (const float*)d_in[8];
    const float* v1  = (const float*)d_in[9];
    const float* g2  = (const float*)d_in[10];
    const float* be2 = (const float*)d_in[11];
    const float* m2  = (const float*)d_in[12];
    const float* v2  = (const float*)d_in[13];
    const float* fcW = (const float*)d_in[14];
    const float* fcb = (const float*)d_in[15];
    float* out = (float*)d_out;

    char* ws = (char*)d_ws;
    size_t off = 0;
    auto alloc = [&](size_t b) {
        char* p = ws + off;
        off += (b + 255) & ~(size_t)255;
        return p;
    };
    uint*  h      = (uint*)alloc((size_t)N_NODES * C_H * 2);     // bf16 Hs
    float* x1     = (float*)alloc((size_t)N_NODES * C_H * 4);
    float* x2     = (float*)alloc((size_t)N_NODES * C_H * 4);
    int2*  pairs  = (int2*)alloc((size_t)N_EDGES * 8);
    int*   cols   = (int*)alloc((size_t)N_EDGES * 4);
    float* dinv   = (float*)alloc(N_NODES * 4);
    int*   rowptr = (int*)alloc((N_NODES + 1) * 4);
    int*   bcnt   = (int*)alloc((NB + 1) * 4);
    int*   bstart = (int*)alloc((NB + 1) * 4);
    int*   bfill  = (int*)alloc((NB + 1) * 4);
    float* coef   = (float*)alloc(512 * 4);
    float* s1 = coef, *t1 = coef + 128, *s2 = coef + 256, *t2 = coef + 384;

    const int nwg_bin = (N_EDGES + CHUNK - 1) / CHUNK;   // 261

    zero_i32<<<2, 256, 0, stream>>>(bcnt, NB);
    bucket_count<<<nwg_bin, 256, 0, stream>>>(e_row, bcnt);
    scan_buckets<<<1, 256, 0, stream>>>(bcnt, bstart, bfill);
    bucket_bin<<<nwg_bin, 256, 0, stream>>>(e_row, e_col, bfill, pairs);
    bucket_csr<<<NB, 256, 0, stream>>>(pairs, bstart, rowptr, dinv, cols);
    bn_coef<<<1, 128, 0, stream>>>(b1, g1, be1, m1, v1, b2, g2, be2, m2, v2,
                                   s1, t1, s2, t2);

    gemm_scaled<<<N_NODES / 32, 256, 0, stream>>>(x, W1, dinv, h);
    spmm_bn_relu4<<<N_NODES / 4, 256, 0, stream>>>(h, cols, rowptr, dinv, s1, t1, x1);
    gemm_scaled<<<N_NODES / 32, 256, 0, stream>>>(x1, W2, dinv, h);
    spmm_bn_relu4<<<N_NODES / 4, 256, 0, stream>>>(h, cols, rowptr, dinv, s2, t2, x2);
    final_gemm14<<<(N_NODES + 63) / 64, 256, 0, stream>>>(x, x1, x2, fcW, fcb, out);
}